// Round 2
// 336.562 us; speedup vs baseline: 1.0176x; 1.0176x over previous
//
#include <hip/hip_runtime.h>

// GCN 3-layer forward on gfx950.
// Round 14: R13 (dst-range-partitioned CSR fill) with gather typo fixed.
//  - R13 crashed: gather_k<64> used p23.w (norm float bits) as byte offset
//    for m3 -> ~500MB OOB read -> GPU fault. Restored p23.z.
//  - Fill: 8 replicated passes over edge list; block b keeps only edges with
//    dst in range (b & 7) (~= XCD id under round-robin dispatch). Each XCD
//    writes only a ~1.1 MB contiguous pairs slice -> L2-resident -> stores
//    merge per line before writeback. Edge loads vectorized int4 (4 e/thread).
// GEMM / gather otherwise unchanged (R11/R12).

#define IN_CH 128

typedef __attribute__((ext_vector_type(8))) short bf16x8;
typedef __attribute__((ext_vector_type(4))) float f32x4;

__device__ inline unsigned short f2bf_rne(float f) {
    unsigned u = __float_as_uint(f);
    unsigned r = (u + 0x7FFFu + ((u >> 16) & 1u)) >> 16;
    return (unsigned short)r;
}
__device__ inline float bf2f(unsigned short h) {
    return __uint_as_float(((unsigned)h) << 16);
}
__device__ inline float bf2f_lo(unsigned m) {
    return __uint_as_float(m << 16);
}
__device__ inline float bf2f_hi(unsigned m) {
    return __uint_as_float(m & 0xffff0000u);
}

// ---------------- degree count ----------------
__global__ __launch_bounds__(256) void cnt_k(const int* __restrict__ dst,
                                             int* __restrict__ cnt, int E) {
    int e = blockIdx.x * 256 + threadIdx.x;
    if (e < E) atomicAdd(&cnt[dst[e]], 1);
}

// ---------------- scan stage 1 on PADDED counts (+ dinv from real) --------
__global__ __launch_bounds__(256) void scan1_k(const int* __restrict__ cnt,
                                               int* __restrict__ bsum,
                                               float* __restrict__ dinv, int N) {
    __shared__ int s[256];
    int tid = threadIdx.x;
    int i = blockIdx.x * 256 + tid;
    int vr = (i < N) ? cnt[i] : 0;
    if (i < N) dinv[i] = rsqrtf((float)vr + 1.0f);
    s[tid] = (i < N) ? ((vr + 3) & ~3) : 0;  // padded count
    __syncthreads();
    for (int off = 128; off > 0; off >>= 1) {
        if (tid < off) s[tid] += s[tid + off];
        __syncthreads();
    }
    if (tid == 0) bsum[blockIdx.x] = s[0];
}

__global__ __launch_bounds__(512) void scan2_k(int* __restrict__ bsum, int nb) {
    __shared__ int s[512];
    __shared__ int carry_s;
    int tid = threadIdx.x;
    if (tid == 0) carry_s = 0;
    __syncthreads();
    for (int base = 0; base < nb; base += 512) {
        int c = carry_s;
        int i = base + tid;
        int v = (i < nb) ? bsum[i] : 0;
        s[tid] = v;
        __syncthreads();
        for (int off = 1; off < 512; off <<= 1) {
            int t = (tid >= off) ? s[tid - off] : 0;
            __syncthreads();
            s[tid] += t;
            __syncthreads();
        }
        if (i < nb) bsum[i] = s[tid] - v + c;
        __syncthreads();
        if (tid == 0) carry_s = c + s[511];
        __syncthreads();
    }
}

// scan3: padded exclusive scan -> rowstart[N+1] (preserved) + cur[N] (cursor)
__global__ __launch_bounds__(256) void scan3_k(const int* __restrict__ cnt,
                                               const int* __restrict__ bsum,
                                               int* __restrict__ rowstart,
                                               int* __restrict__ cur, int N) {
    __shared__ int s[256];
    int tid = threadIdx.x;
    int i = blockIdx.x * 256 + tid;
    int v = (i < N) ? ((cnt[i] + 3) & ~3) : 0;
    s[tid] = v;
    __syncthreads();
    for (int off = 1; off < 256; off <<= 1) {
        int t = (tid >= off) ? s[tid - off] : 0;
        __syncthreads();
        s[tid] += t;
        __syncthreads();
    }
    if (i < N) {
        int st = s[tid] - v + bsum[blockIdx.x];
        rowstart[i] = st;
        cur[i] = st;
        if (i == N - 1) rowstart[N] = st + v;
    }
}

// ---------------- fill (CSR pairs, byte offsets) + W conversion ------------
// Partitioned: 8 replicated passes over the edge list; block b keeps only
// edges with dst in range (b & 7). Under round-robin blockIdx->XCD dispatch,
// each XCD's scatter writes land in a ~1.1 MB L2-resident pairs slice so
// the ~6 stores per 64B line merge before HBM writeback.
__device__ inline void convw_one(const float* W, unsigned short* hi, int FOUT, int id) {
    int n = id >> 7, k = id & 127;
    hi[id] = f2bf_rne(W[k * FOUT + n]);
}

__global__ __launch_bounds__(256) void fill_conv_k(
    const int* __restrict__ src, const int* __restrict__ dst,
    const float* __restrict__ dinv, int* __restrict__ cur,
    int2* __restrict__ pairs, int E, int fillBlocks, int rangeSz,
    const float* __restrict__ W1, const float* __restrict__ W2,
    const float* __restrict__ W3,
    unsigned short* __restrict__ W1h, unsigned short* __restrict__ W2h,
    unsigned short* __restrict__ W3h) {
    if ((int)blockIdx.x < fillBlocks) {
        const int range = blockIdx.x & 7;           // ~= XCD id
        const int lo = range * rangeSz;
        const int hi = lo + rangeSz;
        const int e0 = (blockIdx.x >> 3) * 1024 + threadIdx.x * 4;
        if (e0 >= E) return;
        int s[4], d[4];
        if (e0 + 4 <= E) {
            int4 s4 = *(const int4*)(src + e0);
            int4 d4 = *(const int4*)(dst + e0);
            s[0] = s4.x; s[1] = s4.y; s[2] = s4.z; s[3] = s4.w;
            d[0] = d4.x; d[1] = d4.y; d[2] = d4.z; d[3] = d4.w;
        } else {
#pragma unroll
            for (int k = 0; k < 4; ++k) {
                s[k] = (e0 + k < E) ? src[e0 + k] : 0;
                d[k] = (e0 + k < E) ? dst[e0 + k] : -1;  // never in range
            }
        }
#pragma unroll
        for (int k = 0; k < 4; ++k) {
            if (d[k] >= lo && d[k] < hi) {
                float nrm = dinv[s[k]] * dinv[d[k]];
                int pos = atomicAdd(&cur[d[k]], 1);
                pairs[pos] = make_int2(s[k] * 256, __float_as_int(nrm));  // byte offset
            }
        }
    } else {
        int id = (blockIdx.x - fillBlocks) * 256 + threadIdx.x;
        if (id < 16384) convw_one(W1, W1h, 128, id);
        else if (id < 32768) convw_one(W2, W2h, 128, id - 16384);
        else if (id < 40960) convw_one(W3, W3h, 64, id - 32768);
    }
}

// ---------------- MFMA GEMM: T[N][FOUT] = A[N][128] @ W[128][FOUT] ----------
// C = Ah*Bh, fp32 acc, output bf16 hi only. Block = 4 waves x 16 rows.
// Bh staged in LDS (R8); LDS-staged coalesced epilogue (R10).
__device__ inline bf16x8 cvt8(const float* __restrict__ p) {
    float4 v0 = *(const float4*)p;
    float4 v1 = *(const float4*)(p + 4);
    bf16x8 h;
    h[0] = (short)f2bf_rne(v0.x); h[1] = (short)f2bf_rne(v0.y);
    h[2] = (short)f2bf_rne(v0.z); h[3] = (short)f2bf_rne(v0.w);
    h[4] = (short)f2bf_rne(v1.x); h[5] = (short)f2bf_rne(v1.y);
    h[6] = (short)f2bf_rne(v1.z); h[7] = (short)f2bf_rne(v1.w);
    return h;
}

template <int FOUT, bool AF32>
__global__ __launch_bounds__(256) void mfma_gemm(const float* __restrict__ Af,
                                                 const unsigned short* __restrict__ Ahi,
                                                 const unsigned short* __restrict__ Bhi,
                                                 unsigned short* __restrict__ Thi,
                                                 int N) {
    constexpr int NCT = FOUT / 16;
    constexpr int BSTRIDE = 136;
    constexpr int CSTRIDE = FOUT + 8;
    constexpr int BU = FOUT * BSTRIDE;
    constexpr int CU = 64 * CSTRIDE;
    constexpr int SMEMU = (BU > CU) ? BU : CU;
    __shared__ unsigned short smem[SMEMU];

    const int tid = threadIdx.x;
    const int wv = tid >> 6, lane = tid & 63;
    const int quad = lane >> 4, l16 = lane & 15;
    const int row0 = blockIdx.x * 64 + wv * 16;

#pragma unroll
    for (int it = 0; it < FOUT / 16; ++it) {
        int i = it * 256 + tid;
        int r = i >> 4, c = (i & 15) * 8;
        *(bf16x8*)(&smem[r * BSTRIDE + c]) = *(const bf16x8*)(Bhi + (size_t)r * 128 + c);
    }
    __syncthreads();

    f32x4 acc[NCT];
#pragma unroll
    for (int ct = 0; ct < NCT; ++ct)
        acc[ct] = (f32x4){0.f, 0.f, 0.f, 0.f};

    const int ra = AF32 ? min(row0 + l16, N - 1) : (row0 + l16);

#pragma unroll
    for (int ks = 0; ks < 4; ++ks) {
        const int ko = ks * 32 + quad * 8;
        bf16x8 ah;
        if (AF32) {
            ah = cvt8(Af + (size_t)ra * 128 + ko);
        } else {
            ah = *(const bf16x8*)(Ahi + (size_t)ra * 128 + ko);
        }
#pragma unroll
        for (int ct = 0; ct < NCT; ++ct) {
            bf16x8 bh = *(const bf16x8*)(&smem[(ct * 16 + l16) * BSTRIDE + ko]);
            acc[ct] = __builtin_amdgcn_mfma_f32_16x16x32_bf16(ah, bh, acc[ct], 0, 0, 0);
        }
    }

    __syncthreads();
    const int lrow = wv * 16 + quad * 4;
#pragma unroll
    for (int ct = 0; ct < NCT; ++ct) {
        const int col = ct * 16 + l16;
#pragma unroll
        for (int r = 0; r < 4; ++r)
            smem[(lrow + r) * CSTRIDE + col] = f2bf_rne(acc[ct][r]);
    }
    __syncthreads();
    constexpr int CH = FOUT / 8;
#pragma unroll
    for (int i = 0; i < 64 * CH / 256; ++i) {
        int ci = i * 256 + tid;
        int r = ci / CH, c = (ci % CH) * 8;
        int grow = blockIdx.x * 64 + r;
        if (grow < N)
            *(uint4*)(Thi + (size_t)grow * FOUT + c) = *(const uint4*)&smem[r * CSTRIDE + c];
    }
}

// ---------------- aggregation: wave per row, branchless 4-unrolled ---------
// res[row] = b + Thi[row]*dinv^2 + sum_e norm_e * Thi@off_e
// Rows padded to 4-multiples with (off=0, norm=0) pad edges.
template <int FOUT, bool SPLIT>
__global__ __launch_bounds__(256) void gather_k(const int* __restrict__ rowstart,
                                                const int2* __restrict__ pairs,
                                                const float* __restrict__ dinv,
                                                const unsigned short* __restrict__ Thi,
                                                const float* __restrict__ bias,
                                                float* __restrict__ out,
                                                unsigned short* __restrict__ outHi,
                                                int N) {
    const int wave = threadIdx.x >> 6;
    const int lane = threadIdx.x & 63;
    const int row = blockIdx.x * 4 + wave;
    if (row >= N) return;

    const int start = rowstart[row];
    const int end = rowstart[row + 1];
    const float dr = dinv[row];
    const char* tbase = (const char*)Thi;

    if (FOUT == 128) {
        const int laneB = lane * 4;  // dword per lane
        unsigned sh = *(const unsigned*)(tbase + (size_t)row * 256 + laneB);
        float2 bb = *(const float2*)(bias + lane * 2);
        float ax = bb.x + bf2f_lo(sh) * dr * dr;
        float ay = bb.y + bf2f_hi(sh) * dr * dr;

        for (int j = start; j < end; j += 4) {
            int4 p01 = *(const int4*)(pairs + j);
            int4 p23 = *(const int4*)(pairs + j + 2);
            unsigned m0 = *(const unsigned*)(tbase + (unsigned)p01.x + laneB);
            unsigned m1 = *(const unsigned*)(tbase + (unsigned)p01.z + laneB);
            unsigned m2 = *(const unsigned*)(tbase + (unsigned)p23.x + laneB);
            unsigned m3 = *(const unsigned*)(tbase + (unsigned)p23.z + laneB);
            float n0 = __int_as_float(p01.y), n1 = __int_as_float(p01.w);
            float n2 = __int_as_float(p23.y), n3 = __int_as_float(p23.w);
            ax += n0 * bf2f_lo(m0); ay += n0 * bf2f_hi(m0);
            ax += n1 * bf2f_lo(m1); ay += n1 * bf2f_hi(m1);
            ax += n2 * bf2f_lo(m2); ay += n2 * bf2f_hi(m2);
            ax += n3 * bf2f_lo(m3); ay += n3 * bf2f_hi(m3);
        }

        if (SPLIT) {
            float vx = fmaxf(ax, 0.f), vy = fmaxf(ay, 0.f);
            ushort2 h;
            h.x = f2bf_rne(vx);
            h.y = f2bf_rne(vy);
            *(ushort2*)(outHi + (size_t)row * 128 + lane * 2) = h;
        } else {
            float2 o; o.x = ax; o.y = ay;
            *(float2*)(out + (size_t)row * 128 + lane * 2) = o;
        }
    } else {  // FOUT == 64: rows are 128B; byte offset = off>>1; ushort per lane
        const int laneB = lane * 2;
        float acc = bias[lane] +
                    bf2f(*(const unsigned short*)(tbase + (size_t)row * 128 + laneB)) * dr * dr;

        for (int j = start; j < end; j += 4) {
            int4 p01 = *(const int4*)(pairs + j);
            int4 p23 = *(const int4*)(pairs + j + 2);
            float m0 = bf2f(*(const unsigned short*)(tbase + ((unsigned)p01.x >> 1) + laneB));
            float m1 = bf2f(*(const unsigned short*)(tbase + ((unsigned)p01.z >> 1) + laneB));
            float m2 = bf2f(*(const unsigned short*)(tbase + ((unsigned)p23.x >> 1) + laneB));
            float m3 = bf2f(*(const unsigned short*)(tbase + ((unsigned)p23.z >> 1) + laneB));
            acc += __int_as_float(p01.y) * m0 + __int_as_float(p01.w) * m1 +
                   __int_as_float(p23.y) * m2 + __int_as_float(p23.w) * m3;
        }
        out[(size_t)row * FOUT + lane] = acc;
    }
}

extern "C" void kernel_launch(void* const* d_in, const int* in_sizes, int n_in,
                              void* d_out, int out_size, void* d_ws, size_t ws_size,
                              hipStream_t stream) {
    const float* x  = (const float*)d_in[0];
    const int* eidx = (const int*)d_in[1];
    const float* W1 = (const float*)d_in[2];
    const float* b1 = (const float*)d_in[3];
    const float* W2 = (const float*)d_in[4];
    const float* b2 = (const float*)d_in[5];
    const float* W3 = (const float*)d_in[6];
    const float* b3 = (const float*)d_in[7];
    float* out = (float*)d_out;

    const int N = in_sizes[0] / IN_CH;
    const int E = in_sizes[1] / 2;
    const int* src = eidx;
    const int* dst = eidx + E;
    const int Npad = ((N + 127) / 128) * 128;
    const int nb = (N + 255) / 256;
    const int Emax = E + 3 * N;  // padded-pairs upper bound

    auto align = [](size_t v) { return (v + 255) / 256 * 256; };
    char* p = (char*)d_ws;
    int* cnt = (int*)p;            p += align((size_t)N * 4);
    int* rowstart = (int*)p;       p += align((size_t)(N + 1) * 4);
    int* cur = (int*)p;            p += align((size_t)N * 4);
    int* bsum = (int*)p;           p += align((size_t)nb * 4);
    float* dinv = (float*)p;       p += align((size_t)N * 4);
    int2* pairs = (int2*)p;        p += align((size_t)Emax * 8);
    unsigned short* Ahi = (unsigned short*)p;  p += align((size_t)Npad * 128 * 2);
    unsigned short* Thi = (unsigned short*)p;  p += align((size_t)Npad * 128 * 2);
    unsigned short* W1h = (unsigned short*)p;  p += align(128 * 128 * 2);
    unsigned short* W2h = (unsigned short*)p;  p += align(128 * 128 * 2);
    unsigned short* W3h = (unsigned short*)p;

    // ---- CSR build (once; reused by all 3 layers) ----
    hipMemsetAsync(cnt, 0, (size_t)N * 4, stream);
    hipMemsetAsync(pairs, 0, (size_t)Emax * 8, stream);  // pad edges = (0,0)
    cnt_k<<<(E + 255) / 256, 256, 0, stream>>>(dst, cnt, E);
    scan1_k<<<nb, 256, 0, stream>>>(cnt, bsum, dinv, N);
    scan2_k<<<1, 512, 0, stream>>>(bsum, nb);
    scan3_k<<<nb, 256, 0, stream>>>(cnt, bsum, rowstart, cur, N);
    // partitioned fill: 8 dst-range passes, 4 edges/thread
    const int chunks = (E + 1023) / 1024;
    const int fillBlocks = chunks * 8;
    const int rangeSz = (N + 7) / 8;
    fill_conv_k<<<fillBlocks + 160, 256, 0, stream>>>(src, dst, dinv, cur, pairs,
                                                      E, fillBlocks, rangeSz,
                                                      W1, W2, W3, W1h, W2h, W3h);

    const int gemm_blocks = (N + 63) / 64;
    const int gather_blocks = (N + 3) / 4;

    // Layer 1 (A = x fp32, converted in-register)
    mfma_gemm<128, true><<<gemm_blocks, 256, 0, stream>>>(x, nullptr, W1h, Thi, N);
    gather_k<128, true><<<gather_blocks, 256, 0, stream>>>(rowstart, pairs, dinv, Thi,
                                                           b1, nullptr, Ahi, N);
    // Layer 2
    mfma_gemm<128, false><<<gemm_blocks, 256, 0, stream>>>(nullptr, Ahi, W2h, Thi, N);
    gather_k<128, true><<<gather_blocks, 256, 0, stream>>>(rowstart, pairs, dinv, Thi,
                                                           b2, nullptr, Ahi, N);
    // Layer 3
    mfma_gemm<64, false><<<gemm_blocks, 256, 0, stream>>>(nullptr, Ahi, W3h, Thi, N);
    gather_k<64, false><<<gather_blocks, 256, 0, stream>>>(rowstart, pairs, dinv, Thi,
                                                           b3, out, nullptr, N);
}

// Round 3
// 327.273 us; speedup vs baseline: 1.0465x; 1.0284x over previous
//
#include <hip/hip_runtime.h>

// GCN 3-layer forward on gfx950.
// Round 15: gather latency-chain attack.
//  - R14 counters: gather_k 3x44.8us, 3 TB/s, VALU 32%, nothing saturated ->
//    latency-bound on 2 serialized memory round-trips per 4-edge iteration
//    (pairs load -> addr -> row loads) x ~2.5 iters/row.
//  - Rows now padded to multiples of 8 (scan1/scan3: (v+7)&~7, Emax=E+7N):
//    ~1.45 iters/row.
//  - 8-edge unrolled loop with software-pipelined pairs prefetch: row loads
//    issued first, next batch's pairs after -> compiler's counted vmcnt hides
//    pairs latency under the row-load round trip (~1 RT/iter).
// Fill (R13/R14 partitioned) and GEMM unchanged.

#define IN_CH 128

typedef __attribute__((ext_vector_type(8))) short bf16x8;
typedef __attribute__((ext_vector_type(4))) float f32x4;

__device__ inline unsigned short f2bf_rne(float f) {
    unsigned u = __float_as_uint(f);
    unsigned r = (u + 0x7FFFu + ((u >> 16) & 1u)) >> 16;
    return (unsigned short)r;
}
__device__ inline float bf2f(unsigned short h) {
    return __uint_as_float(((unsigned)h) << 16);
}
__device__ inline float bf2f_lo(unsigned m) {
    return __uint_as_float(m << 16);
}
__device__ inline float bf2f_hi(unsigned m) {
    return __uint_as_float(m & 0xffff0000u);
}

// ---------------- degree count ----------------
__global__ __launch_bounds__(256) void cnt_k(const int* __restrict__ dst,
                                             int* __restrict__ cnt, int E) {
    int e = blockIdx.x * 256 + threadIdx.x;
    if (e < E) atomicAdd(&cnt[dst[e]], 1);
}

// ---------------- scan stage 1 on PADDED counts (+ dinv from real) --------
__global__ __launch_bounds__(256) void scan1_k(const int* __restrict__ cnt,
                                               int* __restrict__ bsum,
                                               float* __restrict__ dinv, int N) {
    __shared__ int s[256];
    int tid = threadIdx.x;
    int i = blockIdx.x * 256 + tid;
    int vr = (i < N) ? cnt[i] : 0;
    if (i < N) dinv[i] = rsqrtf((float)vr + 1.0f);
    s[tid] = (i < N) ? ((vr + 7) & ~7) : 0;  // padded count (8)
    __syncthreads();
    for (int off = 128; off > 0; off >>= 1) {
        if (tid < off) s[tid] += s[tid + off];
        __syncthreads();
    }
    if (tid == 0) bsum[blockIdx.x] = s[0];
}

__global__ __launch_bounds__(512) void scan2_k(int* __restrict__ bsum, int nb) {
    __shared__ int s[512];
    __shared__ int carry_s;
    int tid = threadIdx.x;
    if (tid == 0) carry_s = 0;
    __syncthreads();
    for (int base = 0; base < nb; base += 512) {
        int c = carry_s;
        int i = base + tid;
        int v = (i < nb) ? bsum[i] : 0;
        s[tid] = v;
        __syncthreads();
        for (int off = 1; off < 512; off <<= 1) {
            int t = (tid >= off) ? s[tid - off] : 0;
            __syncthreads();
            s[tid] += t;
            __syncthreads();
        }
        if (i < nb) bsum[i] = s[tid] - v + c;
        __syncthreads();
        if (tid == 0) carry_s = c + s[511];
        __syncthreads();
    }
}

// scan3: padded exclusive scan -> rowstart[N+1] (preserved) + cur[N] (cursor)
__global__ __launch_bounds__(256) void scan3_k(const int* __restrict__ cnt,
                                               const int* __restrict__ bsum,
                                               int* __restrict__ rowstart,
                                               int* __restrict__ cur, int N) {
    __shared__ int s[256];
    int tid = threadIdx.x;
    int i = blockIdx.x * 256 + tid;
    int v = (i < N) ? ((cnt[i] + 7) & ~7) : 0;
    s[tid] = v;
    __syncthreads();
    for (int off = 1; off < 256; off <<= 1) {
        int t = (tid >= off) ? s[tid - off] : 0;
        __syncthreads();
        s[tid] += t;
        __syncthreads();
    }
    if (i < N) {
        int st = s[tid] - v + bsum[blockIdx.x];
        rowstart[i] = st;
        cur[i] = st;
        if (i == N - 1) rowstart[N] = st + v;
    }
}

// ---------------- fill (CSR pairs, byte offsets) + W conversion ------------
// Partitioned: 8 replicated passes over the edge list; block b keeps only
// edges with dst in range (b & 7) (~= XCD id under round-robin dispatch).
__device__ inline void convw_one(const float* W, unsigned short* hi, int FOUT, int id) {
    int n = id >> 7, k = id & 127;
    hi[id] = f2bf_rne(W[k * FOUT + n]);
}

__global__ __launch_bounds__(256) void fill_conv_k(
    const int* __restrict__ src, const int* __restrict__ dst,
    const float* __restrict__ dinv, int* __restrict__ cur,
    int2* __restrict__ pairs, int E, int fillBlocks, int rangeSz,
    const float* __restrict__ W1, const float* __restrict__ W2,
    const float* __restrict__ W3,
    unsigned short* __restrict__ W1h, unsigned short* __restrict__ W2h,
    unsigned short* __restrict__ W3h) {
    if ((int)blockIdx.x < fillBlocks) {
        const int range = blockIdx.x & 7;           // ~= XCD id
        const int lo = range * rangeSz;
        const int hi = lo + rangeSz;
        const int e0 = (blockIdx.x >> 3) * 1024 + threadIdx.x * 4;
        if (e0 >= E) return;
        int s[4], d[4];
        if (e0 + 4 <= E) {
            int4 s4 = *(const int4*)(src + e0);
            int4 d4 = *(const int4*)(dst + e0);
            s[0] = s4.x; s[1] = s4.y; s[2] = s4.z; s[3] = s4.w;
            d[0] = d4.x; d[1] = d4.y; d[2] = d4.z; d[3] = d4.w;
        } else {
#pragma unroll
            for (int k = 0; k < 4; ++k) {
                s[k] = (e0 + k < E) ? src[e0 + k] : 0;
                d[k] = (e0 + k < E) ? dst[e0 + k] : -1;  // never in range
            }
        }
#pragma unroll
        for (int k = 0; k < 4; ++k) {
            if (d[k] >= lo && d[k] < hi) {
                float nrm = dinv[s[k]] * dinv[d[k]];
                int pos = atomicAdd(&cur[d[k]], 1);
                pairs[pos] = make_int2(s[k] * 256, __float_as_int(nrm));  // byte offset
            }
        }
    } else {
        int id = (blockIdx.x - fillBlocks) * 256 + threadIdx.x;
        if (id < 16384) convw_one(W1, W1h, 128, id);
        else if (id < 32768) convw_one(W2, W2h, 128, id - 16384);
        else if (id < 40960) convw_one(W3, W3h, 64, id - 32768);
    }
}

// ---------------- MFMA GEMM: T[N][FOUT] = A[N][128] @ W[128][FOUT] ----------
__device__ inline bf16x8 cvt8(const float* __restrict__ p) {
    float4 v0 = *(const float4*)p;
    float4 v1 = *(const float4*)(p + 4);
    bf16x8 h;
    h[0] = (short)f2bf_rne(v0.x); h[1] = (short)f2bf_rne(v0.y);
    h[2] = (short)f2bf_rne(v0.z); h[3] = (short)f2bf_rne(v0.w);
    h[4] = (short)f2bf_rne(v1.x); h[5] = (short)f2bf_rne(v1.y);
    h[6] = (short)f2bf_rne(v1.z); h[7] = (short)f2bf_rne(v1.w);
    return h;
}

template <int FOUT, bool AF32>
__global__ __launch_bounds__(256) void mfma_gemm(const float* __restrict__ Af,
                                                 const unsigned short* __restrict__ Ahi,
                                                 const unsigned short* __restrict__ Bhi,
                                                 unsigned short* __restrict__ Thi,
                                                 int N) {
    constexpr int NCT = FOUT / 16;
    constexpr int BSTRIDE = 136;
    constexpr int CSTRIDE = FOUT + 8;
    constexpr int BU = FOUT * BSTRIDE;
    constexpr int CU = 64 * CSTRIDE;
    constexpr int SMEMU = (BU > CU) ? BU : CU;
    __shared__ unsigned short smem[SMEMU];

    const int tid = threadIdx.x;
    const int wv = tid >> 6, lane = tid & 63;
    const int quad = lane >> 4, l16 = lane & 15;
    const int row0 = blockIdx.x * 64 + wv * 16;

#pragma unroll
    for (int it = 0; it < FOUT / 16; ++it) {
        int i = it * 256 + tid;
        int r = i >> 4, c = (i & 15) * 8;
        *(bf16x8*)(&smem[r * BSTRIDE + c]) = *(const bf16x8*)(Bhi + (size_t)r * 128 + c);
    }
    __syncthreads();

    f32x4 acc[NCT];
#pragma unroll
    for (int ct = 0; ct < NCT; ++ct)
        acc[ct] = (f32x4){0.f, 0.f, 0.f, 0.f};

    const int ra = AF32 ? min(row0 + l16, N - 1) : (row0 + l16);

#pragma unroll
    for (int ks = 0; ks < 4; ++ks) {
        const int ko = ks * 32 + quad * 8;
        bf16x8 ah;
        if (AF32) {
            ah = cvt8(Af + (size_t)ra * 128 + ko);
        } else {
            ah = *(const bf16x8*)(Ahi + (size_t)ra * 128 + ko);
        }
#pragma unroll
        for (int ct = 0; ct < NCT; ++ct) {
            bf16x8 bh = *(const bf16x8*)(&smem[(ct * 16 + l16) * BSTRIDE + ko]);
            acc[ct] = __builtin_amdgcn_mfma_f32_16x16x32_bf16(ah, bh, acc[ct], 0, 0, 0);
        }
    }

    __syncthreads();
    const int lrow = wv * 16 + quad * 4;
#pragma unroll
    for (int ct = 0; ct < NCT; ++ct) {
        const int col = ct * 16 + l16;
#pragma unroll
        for (int r = 0; r < 4; ++r)
            smem[(lrow + r) * CSTRIDE + col] = f2bf_rne(acc[ct][r]);
    }
    __syncthreads();
    constexpr int CH = FOUT / 8;
#pragma unroll
    for (int i = 0; i < 64 * CH / 256; ++i) {
        int ci = i * 256 + tid;
        int r = ci / CH, c = (ci % CH) * 8;
        int grow = blockIdx.x * 64 + r;
        if (grow < N)
            *(uint4*)(Thi + (size_t)grow * FOUT + c) = *(const uint4*)&smem[r * CSTRIDE + c];
    }
}

// ---------------- aggregation: wave per row, 8-unrolled + pairs prefetch ---
// res[row] = b + Thi[row]*dinv^2 + sum_e norm_e * Thi@off_e
// Rows padded to 8-multiples with (off=0, norm=0) pad edges.
// pairs has >=16 entries of slack past the last row, so the pipeline's
// prefetch past `end` stays in-bounds (values discarded).
template <int FOUT, bool SPLIT>
__global__ __launch_bounds__(256) void gather_k(const int* __restrict__ rowstart,
                                                const int2* __restrict__ pairs,
                                                const float* __restrict__ dinv,
                                                const unsigned short* __restrict__ Thi,
                                                const float* __restrict__ bias,
                                                float* __restrict__ out,
                                                unsigned short* __restrict__ outHi,
                                                int N) {
    const int wave = threadIdx.x >> 6;
    const int lane = threadIdx.x & 63;
    const int row = blockIdx.x * 4 + wave;
    if (row >= N) return;

    const int start = rowstart[row];
    const int end = rowstart[row + 1];
    const float dr = dinv[row];
    const char* tbase = (const char*)Thi;

    if (FOUT == 128) {
        const int laneB = lane * 4;  // dword per lane
        unsigned sh = *(const unsigned*)(tbase + (size_t)row * 256 + laneB);
        float2 bb = *(const float2*)(bias + lane * 2);
        float ax = bb.x + bf2f_lo(sh) * dr * dr;
        float ay = bb.y + bf2f_hi(sh) * dr * dr;

        int4 p0 = *(const int4*)(pairs + start);
        int4 p1 = *(const int4*)(pairs + start + 2);
        int4 p2 = *(const int4*)(pairs + start + 4);
        int4 p3 = *(const int4*)(pairs + start + 6);
        for (int j = start; j < end;) {
            const int jn = j + 8;
            // row loads for current batch (addresses ready in regs)
            unsigned m0 = *(const unsigned*)(tbase + (unsigned)p0.x + laneB);
            unsigned m1 = *(const unsigned*)(tbase + (unsigned)p0.z + laneB);
            unsigned m2 = *(const unsigned*)(tbase + (unsigned)p1.x + laneB);
            unsigned m3 = *(const unsigned*)(tbase + (unsigned)p1.z + laneB);
            unsigned m4 = *(const unsigned*)(tbase + (unsigned)p2.x + laneB);
            unsigned m5 = *(const unsigned*)(tbase + (unsigned)p2.z + laneB);
            unsigned m6 = *(const unsigned*)(tbase + (unsigned)p3.x + laneB);
            unsigned m7 = *(const unsigned*)(tbase + (unsigned)p3.z + laneB);
            // prefetch next batch's pairs (issued after row loads -> latency
            // hides under them; discarded past end, in-bounds via slack)
            int4 q0 = *(const int4*)(pairs + jn);
            int4 q1 = *(const int4*)(pairs + jn + 2);
            int4 q2 = *(const int4*)(pairs + jn + 4);
            int4 q3 = *(const int4*)(pairs + jn + 6);
            float n0 = __int_as_float(p0.y), n1 = __int_as_float(p0.w);
            float n2 = __int_as_float(p1.y), n3 = __int_as_float(p1.w);
            float n4 = __int_as_float(p2.y), n5 = __int_as_float(p2.w);
            float n6 = __int_as_float(p3.y), n7 = __int_as_float(p3.w);
            ax += n0 * bf2f_lo(m0); ay += n0 * bf2f_hi(m0);
            ax += n1 * bf2f_lo(m1); ay += n1 * bf2f_hi(m1);
            ax += n2 * bf2f_lo(m2); ay += n2 * bf2f_hi(m2);
            ax += n3 * bf2f_lo(m3); ay += n3 * bf2f_hi(m3);
            ax += n4 * bf2f_lo(m4); ay += n4 * bf2f_hi(m4);
            ax += n5 * bf2f_lo(m5); ay += n5 * bf2f_hi(m5);
            ax += n6 * bf2f_lo(m6); ay += n6 * bf2f_hi(m6);
            ax += n7 * bf2f_lo(m7); ay += n7 * bf2f_hi(m7);
            p0 = q0; p1 = q1; p2 = q2; p3 = q3;
            j = jn;
        }

        if (SPLIT) {
            float vx = fmaxf(ax, 0.f), vy = fmaxf(ay, 0.f);
            ushort2 h;
            h.x = f2bf_rne(vx);
            h.y = f2bf_rne(vy);
            *(ushort2*)(outHi + (size_t)row * 128 + lane * 2) = h;
        } else {
            float2 o; o.x = ax; o.y = ay;
            *(float2*)(out + (size_t)row * 128 + lane * 2) = o;
        }
    } else {  // FOUT == 64: rows are 128B; byte offset = off>>1; ushort per lane
        const int laneB = lane * 2;
        float acc = bias[lane] +
                    bf2f(*(const unsigned short*)(tbase + (size_t)row * 128 + laneB)) * dr * dr;

        int4 p0 = *(const int4*)(pairs + start);
        int4 p1 = *(const int4*)(pairs + start + 2);
        int4 p2 = *(const int4*)(pairs + start + 4);
        int4 p3 = *(const int4*)(pairs + start + 6);
        for (int j = start; j < end;) {
            const int jn = j + 8;
            float m0 = bf2f(*(const unsigned short*)(tbase + ((unsigned)p0.x >> 1) + laneB));
            float m1 = bf2f(*(const unsigned short*)(tbase + ((unsigned)p0.z >> 1) + laneB));
            float m2 = bf2f(*(const unsigned short*)(tbase + ((unsigned)p1.x >> 1) + laneB));
            float m3 = bf2f(*(const unsigned short*)(tbase + ((unsigned)p1.z >> 1) + laneB));
            float m4 = bf2f(*(const unsigned short*)(tbase + ((unsigned)p2.x >> 1) + laneB));
            float m5 = bf2f(*(const unsigned short*)(tbase + ((unsigned)p2.z >> 1) + laneB));
            float m6 = bf2f(*(const unsigned short*)(tbase + ((unsigned)p3.x >> 1) + laneB));
            float m7 = bf2f(*(const unsigned short*)(tbase + ((unsigned)p3.z >> 1) + laneB));
            int4 q0 = *(const int4*)(pairs + jn);
            int4 q1 = *(const int4*)(pairs + jn + 2);
            int4 q2 = *(const int4*)(pairs + jn + 4);
            int4 q3 = *(const int4*)(pairs + jn + 6);
            acc += __int_as_float(p0.y) * m0 + __int_as_float(p0.w) * m1 +
                   __int_as_float(p1.y) * m2 + __int_as_float(p1.w) * m3 +
                   __int_as_float(p2.y) * m4 + __int_as_float(p2.w) * m5 +
                   __int_as_float(p3.y) * m6 + __int_as_float(p3.w) * m7;
            p0 = q0; p1 = q1; p2 = q2; p3 = q3;
            j = jn;
        }
        out[(size_t)row * FOUT + lane] = acc;
    }
}

extern "C" void kernel_launch(void* const* d_in, const int* in_sizes, int n_in,
                              void* d_out, int out_size, void* d_ws, size_t ws_size,
                              hipStream_t stream) {
    const float* x  = (const float*)d_in[0];
    const int* eidx = (const int*)d_in[1];
    const float* W1 = (const float*)d_in[2];
    const float* b1 = (const float*)d_in[3];
    const float* W2 = (const float*)d_in[4];
    const float* b2 = (const float*)d_in[5];
    const float* W3 = (const float*)d_in[6];
    const float* b3 = (const float*)d_in[7];
    float* out = (float*)d_out;

    const int N = in_sizes[0] / IN_CH;
    const int E = in_sizes[1] / 2;
    const int* src = eidx;
    const int* dst = eidx + E;
    const int Npad = ((N + 127) / 128) * 128;
    const int nb = (N + 255) / 256;
    const int Emax = E + 7 * N + 16;  // 8-padded pairs upper bound + pipeline slack

    auto align = [](size_t v) { return (v + 255) / 256 * 256; };
    char* p = (char*)d_ws;
    int* cnt = (int*)p;            p += align((size_t)N * 4);
    int* rowstart = (int*)p;       p += align((size_t)(N + 1) * 4);
    int* cur = (int*)p;            p += align((size_t)N * 4);
    int* bsum = (int*)p;           p += align((size_t)nb * 4);
    float* dinv = (float*)p;       p += align((size_t)N * 4);
    int2* pairs = (int2*)p;        p += align((size_t)Emax * 8);
    unsigned short* Ahi = (unsigned short*)p;  p += align((size_t)Npad * 128 * 2);
    unsigned short* Thi = (unsigned short*)p;  p += align((size_t)Npad * 128 * 2);
    unsigned short* W1h = (unsigned short*)p;  p += align(128 * 128 * 2);
    unsigned short* W2h = (unsigned short*)p;  p += align(128 * 128 * 2);
    unsigned short* W3h = (unsigned short*)p;

    // ---- CSR build (once; reused by all 3 layers) ----
    hipMemsetAsync(cnt, 0, (size_t)N * 4, stream);
    hipMemsetAsync(pairs, 0, (size_t)Emax * 8, stream);  // pad edges = (0,0)
    cnt_k<<<(E + 255) / 256, 256, 0, stream>>>(dst, cnt, E);
    scan1_k<<<nb, 256, 0, stream>>>(cnt, bsum, dinv, N);
    scan2_k<<<1, 512, 0, stream>>>(bsum, nb);
    scan3_k<<<nb, 256, 0, stream>>>(cnt, bsum, rowstart, cur, N);
    // partitioned fill: 8 dst-range passes, 4 edges/thread
    const int chunks = (E + 1023) / 1024;
    const int fillBlocks = chunks * 8;
    const int rangeSz = (N + 7) / 8;
    fill_conv_k<<<fillBlocks + 160, 256, 0, stream>>>(src, dst, dinv, cur, pairs,
                                                      E, fillBlocks, rangeSz,
                                                      W1, W2, W3, W1h, W2h, W3h);

    const int gemm_blocks = (N + 63) / 64;
    const int gather_blocks = (N + 3) / 4;

    // Layer 1 (A = x fp32, converted in-register)
    mfma_gemm<128, true><<<gemm_blocks, 256, 0, stream>>>(x, nullptr, W1h, Thi, N);
    gather_k<128, true><<<gather_blocks, 256, 0, stream>>>(rowstart, pairs, dinv, Thi,
                                                           b1, nullptr, Ahi, N);
    // Layer 2
    mfma_gemm<128, false><<<gemm_blocks, 256, 0, stream>>>(nullptr, Ahi, W2h, Thi, N);
    gather_k<128, true><<<gather_blocks, 256, 0, stream>>>(rowstart, pairs, dinv, Thi,
                                                           b2, nullptr, Ahi, N);
    // Layer 3
    mfma_gemm<64, false><<<gemm_blocks, 256, 0, stream>>>(nullptr, Ahi, W3h, Thi, N);
    gather_k<64, false><<<gather_blocks, 256, 0, stream>>>(rowstart, pairs, dinv, Thi,
                                                           b3, out, nullptr, N);
}